// Round 2
// baseline (171.032 us; speedup 1.0000x reference)
//
#include <hip/hip_runtime.h>

#define IMG_W 1024
#define IMG_H 1024
#define RPB   4   // output rows per block

__global__ __launch_bounds__(256) void dir_rhs_kernel(
    const float* __restrict__ u,
    const float* __restrict__ f,
    const float* __restrict__ wt,
    float* __restrict__ out)
{
    // Compact halo exchange: per staged row, each thread publishes its
    // first (.x) and last (.w) column. 8B lane stride -> 2-way bank
    // aliasing only (free on CDNA4).
    __shared__ float2 halo[RPB + 2][256];

    const int tid = threadIdx.x;         // 0..255
    const int j0  = tid << 2;            // 4 cols per thread
    const int gb  = blockIdx.x;          // b*256 + rowgroup
    const int b   = gb >> 8;
    const int r0  = (gb & 255) << 2;     // first output row of this block
    const size_t img = (size_t)b << 20;

    const float w00 = wt[0], w01 = wt[1], w02 = wt[2];
    const float w10 = wt[3], w11 = wt[4], w12 = wt[5];
    const float w20 = wt[6], w21 = wt[7], w22 = wt[8];
    const float cof = (float)(-(1.0 / 1023.0) * (1.0 / 1023.0) / 4.0);

    // ---- stage 6 u-rows (r0-1 .. r0+4) as v (boundary ring = 0) ----
    float4 stage[RPB + 2];
    #pragma unroll
    for (int k = 0; k < RPB + 2; k++) {
        const int grow = r0 - 1 + k;
        if (grow >= 1 && grow <= IMG_H - 2) {
            stage[k] = *(const float4*)(u + img + (size_t)grow * IMG_W + j0);
        } else {
            stage[k] = make_float4(0.f, 0.f, 0.f, 0.f);  // v rows 0/1023 and out-of-range
        }
    }
    // ---- f rows (independent; issue while u loads are in flight) ----
    float4 fr[RPB];
    #pragma unroll
    for (int k = 0; k < RPB; k++) {
        fr[k] = *(const float4*)(f + img + (size_t)(r0 + k) * IMG_W + j0);
    }
    // ---- apply column-boundary zeroing of v, publish halos ----
    #pragma unroll
    for (int k = 0; k < RPB + 2; k++) {
        if (tid == 0)   stage[k].x = 0.f;   // col 0 is boundary in v
        if (tid == 255) stage[k].w = 0.f;   // col 1023 is boundary in v
        halo[k][tid] = make_float2(stage[k].x, stage[k].w);
    }
    __syncthreads();

    // Clamped neighbor indices: edge values feed only into outputs that
    // are overwritten with the Dirichlet value anyway.
    const int tl = (tid == 0)   ? 0   : tid - 1;
    const int tr = (tid == 255) ? 255 : tid + 1;

    #pragma unroll
    for (int k = 0; k < RPB; k++) {
        const int grow = r0 + k;
        float4* o4 = (float4*)(out + img + (size_t)grow * IMG_W + j0);
        if (grow == 0 || grow == IMG_H - 1) {      // uniform except groups 0/255
            *o4 = make_float4(0.f, 0.f, 0.f, 0.f);
            continue;
        }
        float vm[6], vc[6], vp[6];
        vm[0] = halo[k    ][tl].y;  vm[5] = halo[k    ][tr].x;
        vc[0] = halo[k + 1][tl].y;  vc[5] = halo[k + 1][tr].x;
        vp[0] = halo[k + 2][tl].y;  vp[5] = halo[k + 2][tr].x;
        vm[1] = stage[k].x;     vm[2] = stage[k].y;     vm[3] = stage[k].z;     vm[4] = stage[k].w;
        vc[1] = stage[k + 1].x; vc[2] = stage[k + 1].y; vc[3] = stage[k + 1].z; vc[4] = stage[k + 1].w;
        vp[1] = stage[k + 2].x; vp[2] = stage[k + 2].y; vp[3] = stage[k + 2].z; vp[4] = stage[k + 2].w;

        const float ff[4] = { fr[k].x, fr[k].y, fr[k].z, fr[k].w };
        float res[4];
        #pragma unroll
        for (int e = 0; e < 4; e++) {
            float acc = cof * ff[e];
            acc += w00 * vm[e] + w01 * vm[e + 1] + w02 * vm[e + 2];
            acc += w10 * vc[e] + w11 * vc[e + 1] + w12 * vc[e + 2];
            acc += w20 * vp[e] + w21 * vp[e + 1] + w22 * vp[e + 2];
            res[e] = acc;
        }
        if (tid == 0)   res[0] = 0.f;   // col 0 boundary
        if (tid == 255) res[3] = 0.f;   // col 1023 boundary
        *o4 = make_float4(res[0], res[1], res[2], res[3]);
    }
}

extern "C" void kernel_launch(void* const* d_in, const int* in_sizes, int n_in,
                              void* d_out, int out_size, void* d_ws, size_t ws_size,
                              hipStream_t stream) {
    const float* u  = (const float*)d_in[0];
    const float* f  = (const float*)d_in[1];
    const float* wt = (const float*)d_in[2];
    float* out = (float*)d_out;

    const int B = 16;
    dim3 grid(B * (IMG_H / RPB));   // 4096 blocks: one per (batch, 4-row group)
    dim3 block(256);                // 256 threads * 4 cols = full 1024-wide row
    dir_rhs_kernel<<<grid, block, 0, stream>>>(u, f, wt, out);
}